// Round 7
// baseline (447.006 us; speedup 1.0000x reference)
//
#include <hip/hip_runtime.h>
#include <hip/hip_bf16.h>

// HoloAttention: out = (Re(cumsum_t(x@Wv^T * e^{i t f}) * e^{-i t f})) @ Wo^T
// (k-projection in reference is dead code — skipped.)
//
// R7: GEMMs split into standalone kernels with __launch_bounds__(256,5)
// (VGPR<=102 -> 5 blocks/CU; R6's 116-VGPR allocation cost a wave slot).
// pass2 folded into pass3 as an L2-resident prefix prologue over raw chunk
// sums (csum no longer updated in place). Chain: cast -> gemm1+sums ->
// pass3 -> gemm2.

#define B_  2
#define T_  8192
#define D_  1024
#define BT_ 16384
#define CS_ 64
#define NCHUNK_ 128

typedef __attribute__((ext_vector_type(4))) float f32x4;
typedef __attribute__((ext_vector_type(8))) short bf16x8;

static __device__ inline unsigned short f2bf(float f) {
    union { float f; unsigned int u; } a;
    a.f = f;
    unsigned int u = a.u;
    return (unsigned short)((u + 0x7FFFu + ((u >> 16) & 1u)) >> 16);  // RNE
}
static __device__ inline float bf2f(unsigned short h) {
    union { unsigned int u; float f; } a;
    a.u = ((unsigned int)h) << 16;
    return a.f;
}

// One fused cast: x (4194304 float4) | Wv (262144) | Wo (262144)
__global__ __launch_bounds__(256) void cast_all(const float* __restrict__ x,
                                                const float* __restrict__ Wv,
                                                const float* __restrict__ Wo,
                                                unsigned short* __restrict__ xb,
                                                unsigned short* __restrict__ wvb,
                                                unsigned short* __restrict__ wob) {
    const int nx = BT_ * D_ / 4;
    const int nw = D_ * D_ / 4;
    int i = blockIdx.x * 256 + threadIdx.x;
    const float4* src;
    unsigned short* dst;
    int j;
    if (i < nx)            { src = (const float4*)x;  dst = xb;  j = i; }
    else if (i < nx + nw)  { src = (const float4*)Wv; dst = wvb; j = i - nx; }
    else                   { src = (const float4*)Wo; dst = wob; j = i - nx - nw; }
    float4 v = src[j];
    ushort4 o;
    o.x = f2bf(v.x); o.y = f2bf(v.y); o.z = f2bf(v.z); o.w = f2bf(v.w);
    ((ushort4*)dst)[j] = o;
}

// ---- shared GEMM macros (4 waves 2x2, wave tile 64x64, block 128x128, BK=64,
// global_load_lds width=16, XCD-swizzled 1-D grid, XOR-swizzled LDS cols) ----
#define GEMM_PROLOGUE(A_, B_ptr, M_, N_, K_)                                     \
    __shared__ short lds[16384];                                                 \
    const int lane = threadIdx.x & 63;                                           \
    const int wave = threadIdx.x >> 6;                                           \
    const int wr = wave >> 1, wc = wave & 1;                                     \
    const int nb = (N_) >> 7;                                                    \
    const int id = blockIdx.x;                                                   \
    const int xcd = id & 7;                                                      \
    const int slot = id >> 3;                                                    \
    const int bn = (slot % nb) * 128;                                            \
    const int bm = (xcd * (((M_) >> 7) >> 3) + slot / nb) * 128;                 \
    const int sr = lane >> 3;                                                    \
    const int cb = lane & 7;                                                     \
    const short* ga[4];                                                          \
    const short* gb[4];                                                          \
    _Pragma("unroll")                                                            \
    for (int cc = 0; cc < 4; ++cc) {                                             \
        const int chunk = wave * 4 + cc;                                         \
        const int row = chunk * 8 + sr;                                          \
        const int col = (cb ^ (row & 7)) * 8;                                    \
        ga[cc] = (A_) + (size_t)(bm + row) * (K_) + col;                         \
        gb[cc] = (B_ptr) + (size_t)(bn + row) * (K_) + col;                      \
    }                                                                            \
    const int c4r = lane >> 4;                                                   \
    int aoff[4][2], boff[4][2];                                                  \
    _Pragma("unroll")                                                            \
    for (int i = 0; i < 4; ++i) {                                                \
        const int m = wr * 64 + (lane & 15) + i * 16;                            \
        const int n = wc * 64 + (lane & 15) + i * 16;                            \
        _Pragma("unroll")                                                        \
        for (int ks = 0; ks < 2; ++ks) {                                         \
            aoff[i][ks] = m * 64 + (((ks * 4 + c4r) ^ (m & 7)) * 8);             \
            boff[i][ks] = 8192 + n * 64 + (((ks * 4 + c4r) ^ (n & 7)) * 8);      \
        }                                                                        \
    }                                                                            \
    f32x4 acc[4][4] = {};                                                        \
    for (int k0 = 0; k0 < (K_); k0 += 64) {                                      \
        _Pragma("unroll")                                                        \
        for (int cc = 0; cc < 4; ++cc) {                                         \
            const int chunk = wave * 4 + cc;                                     \
            __builtin_amdgcn_global_load_lds(                                    \
                (const __attribute__((address_space(1))) void*)(ga[cc] + k0),    \
                (__attribute__((address_space(3))) void*)&lds[chunk * 512], 16, 0, 0); \
            __builtin_amdgcn_global_load_lds(                                    \
                (const __attribute__((address_space(1))) void*)(gb[cc] + k0),    \
                (__attribute__((address_space(3))) void*)&lds[8192 + chunk * 512], 16, 0, 0); \
        }                                                                        \
        __syncthreads();                                                         \
        _Pragma("unroll")                                                        \
        for (int ks = 0; ks < 2; ++ks) {                                         \
            bf16x8 a[4], b[4];                                                   \
            _Pragma("unroll")                                                    \
            for (int i = 0; i < 4; ++i) a[i] = *(const bf16x8*)&lds[aoff[i][ks]];\
            _Pragma("unroll")                                                    \
            for (int j = 0; j < 4; ++j) b[j] = *(const bf16x8*)&lds[boff[j][ks]];\
            _Pragma("unroll")                                                    \
            for (int i = 0; i < 4; ++i)                                          \
                _Pragma("unroll")                                                \
                for (int j = 0; j < 4; ++j)                                      \
                    acc[i][j] = __builtin_amdgcn_mfma_f32_16x16x32_bf16(         \
                        a[i], b[j], acc[i][j], 0, 0, 0);                         \
        }                                                                        \
        __syncthreads();                                                         \
    }

// GEMM1: v = x @ Wv^T (bf16 out) + fused per-64-chunk rotor sums.
__global__ __launch_bounds__(256, 5) void gemm1_fused(const short* __restrict__ A,
                                                      const short* __restrict__ Bm,
                                                      unsigned short* __restrict__ Cout,
                                                      const float* __restrict__ freqs,
                                                      float* __restrict__ csum) {
    GEMM_PROLOGUE(A, Bm, BT_, D_, D_)

    const int row0 = c4r * 4;
#pragma unroll
    for (int i = 0; i < 4; ++i) {
#pragma unroll
        for (int j = 0; j < 4; ++j) {
            const int col = bn + wc * 64 + j * 16 + (lane & 15);
#pragma unroll
            for (int r = 0; r < 4; ++r) {
                const size_t row = bm + wr * 64 + i * 16 + row0 + r;
                Cout[row * D_ + col] = f2bf(acc[i][j][r]);
            }
        }
    }

    // Fused per-chunk rotor sums: wave wr covers t-chunk (trow>>6)+wr.
    const int b = bm >> 13;
    const int trow = bm & 8191;
    const int chunk = (trow >> 6) + wr;
    const int t0 = trow + wr * 64 + c4r * 4;   // absolute t at i=0,r=0
#pragma unroll
    for (int j = 0; j < 4; ++j) {
        const int d = bn + wc * 64 + j * 16 + (lane & 15);
        const float f = freqs[d];
        float ss, cc2;
        sincosf((float)t0 * f, &ss, &cc2);
        float s1, c1;
        sincosf(f, &s1, &c1);
        // e13 = e1^13 via squarings (row steps: +1 within r, +13 across i)
        float c2 = c1 * c1 - s1 * s1, s2 = 2.f * c1 * s1;
        float c4 = c2 * c2 - s2 * s2, s4 = 2.f * c2 * s2;
        float c8 = c4 * c4 - s4 * s4, s8 = 2.f * c4 * s4;
        float c12 = c8 * c4 - s8 * s4, s12 = s8 * c4 + c8 * s4;
        float c13 = c12 * c1 - s12 * s1, s13 = s12 * c1 + c12 * s1;
        float ar = 0.f, ai = 0.f;
        float cr = cc2, sr2 = ss;
#pragma unroll
        for (int i = 0; i < 4; ++i) {
#pragma unroll
            for (int r = 0; r < 4; ++r) {
                const float w = acc[i][j][r];
                ar = fmaf(w, cr, ar); ai = fmaf(w, sr2, ai);
                const float ec = (r < 3) ? c1 : c13;
                const float es = (r < 3) ? s1 : s13;
                const float nc = cr * ec - sr2 * es;
                const float ns = sr2 * ec + cr * es;
                cr = nc; sr2 = ns;
            }
        }
        ar += __shfl_xor(ar, 16); ai += __shfl_xor(ai, 16);
        ar += __shfl_xor(ar, 32); ai += __shfl_xor(ai, 32);
        if (c4r == 0)
            *(float2*)(csum + (((size_t)b * NCHUNK_ + chunk) * D_ + d) * 2) =
                make_float2(ar, ai);
    }
}

// GEMM2: out = ret @ Wo^T (fp32 out), plain epilogue.
__global__ __launch_bounds__(256, 5) void gemm2_plain(const short* __restrict__ A,
                                                      const short* __restrict__ Bm,
                                                      float* __restrict__ Cout) {
    GEMM_PROLOGUE(A, Bm, BT_, D_, D_)

    const int row0 = c4r * 4;
#pragma unroll
    for (int i = 0; i < 4; ++i) {
#pragma unroll
        for (int j = 0; j < 4; ++j) {
            const int col = bn + wc * 64 + j * 16 + (lane & 15);
#pragma unroll
            for (int r = 0; r < 4; ++r) {
                const size_t row = bm + wr * 64 + i * 16 + row0 + r;
                Cout[row * D_ + col] = acc[i][j][r];
            }
        }
    }
}

// Pass 3: exclusive-prefix prologue over raw chunk sums (L2-resident csum),
// then replay chunk; retrieved = Re(mt * conj(rotor)) -> bf16; 2 d's/thread,
// CS=64, 8-row load batches, grid (NCHUNK, D/512, B).
__global__ __launch_bounds__(256) void scan_pass3(const unsigned short* __restrict__ v,
                                                  const float* __restrict__ freqs,
                                                  const float* __restrict__ csum,
                                                  unsigned short* __restrict__ ret) {
    const int chunk = blockIdx.x;
    const int d0 = blockIdx.y * 512 + threadIdx.x * 2;
    const int b = blockIdx.z;

    // prefix of chunk sums for chunks < chunk
    float ar[2] = {0.f, 0.f}, ai[2] = {0.f, 0.f};
    {
        const float* cbase = csum + ((size_t)b * NCHUNK_ * D_ + d0) * 2;
        int cc = 0;
        for (; cc + 8 <= chunk; cc += 8) {
            float4 o[8];
#pragma unroll
            for (int u = 0; u < 8; ++u)
                o[u] = *(const float4*)(cbase + (size_t)(cc + u) * (D_ * 2));
#pragma unroll
            for (int u = 0; u < 8; ++u) {
                ar[0] += o[u].x; ai[0] += o[u].y;
                ar[1] += o[u].z; ai[1] += o[u].w;
            }
        }
        for (; cc < chunk; ++cc) {
            float4 o = *(const float4*)(cbase + (size_t)cc * (D_ * 2));
            ar[0] += o.x; ai[0] += o.y; ar[1] += o.z; ai[1] += o.w;
        }
    }

    float fr[2], s[2], c[2], sf[2], cf[2];
    {
        float2 f2 = *(const float2*)(freqs + d0);
        fr[0] = f2.x; fr[1] = f2.y;
    }
    const float t0f = (float)(chunk * CS_);
#pragma unroll
    for (int k = 0; k < 2; ++k) {
        sincosf(t0f * fr[k], &s[k], &c[k]);
        sincosf(fr[k], &sf[k], &cf[k]);
    }
    const unsigned int* vp = (const unsigned int*)(v + ((size_t)b * T_ + chunk * CS_) * D_ + d0);
    unsigned int* rp = (unsigned int*)(ret + ((size_t)b * T_ + chunk * CS_) * D_ + d0);
    for (int tb = 0; tb < CS_; tb += 8) {
        unsigned int w[8];
#pragma unroll
        for (int u = 0; u < 8; ++u) w[u] = vp[(size_t)(tb + u) * (D_ / 2)];
#pragma unroll
        for (int u = 0; u < 8; ++u) {
            float wv[2], o[2];
            wv[0] = bf2f((unsigned short)w[u]);
            wv[1] = bf2f((unsigned short)(w[u] >> 16));
#pragma unroll
            for (int k = 0; k < 2; ++k) {
                ar[k] = fmaf(wv[k], c[k], ar[k]);
                ai[k] = fmaf(wv[k], s[k], ai[k]);
                o[k] = ar[k] * c[k] + ai[k] * s[k];   // Re(mt * (cos - i sin))
                float nc = c[k] * cf[k] - s[k] * sf[k];
                float ns = s[k] * cf[k] + c[k] * sf[k];
                c[k] = nc; s[k] = ns;
            }
            rp[(size_t)(tb + u) * (D_ / 2)] =
                (unsigned int)f2bf(o[0]) | ((unsigned int)f2bf(o[1]) << 16);
        }
    }
}

extern "C" void kernel_launch(void* const* d_in, const int* in_sizes, int n_in,
                              void* d_out, int out_size, void* d_ws, size_t ws_size,
                              hipStream_t stream) {
    const float* x     = (const float*)d_in[0];
    // d_in[1] = Wk (dead in reference)
    const float* Wv    = (const float*)d_in[2];
    const float* Wo    = (const float*)d_in[3];
    const float* freqs = (const float*)d_in[4];
    float* out = (float*)d_out;

    char* ws = (char*)d_ws;
    unsigned short* x_bf  = (unsigned short*)ws;                 // 33,554,432 B
    unsigned short* Wv_bf = (unsigned short*)(ws + 33554432);    //  2,097,152 B
    unsigned short* Wo_bf = (unsigned short*)(ws + 35651584);    //  2,097,152 B
    unsigned short* ret   = (unsigned short*)(ws + 37748736);    // 33,554,432 B
    float*          csum  = (float*)(ws + 71303168);             //  2,097,152 B (B*128*D*2*4)
    // v (bf16) lives in d_out's first half; dead before GEMM2 overwrites d_out.
    unsigned short* v_bf = (unsigned short*)d_out;

    // 1. fused casts (x | Wv | Wo)
    cast_all<<<(BT_ * D_ / 4 + 2 * D_ * D_ / 4) / 256, 256, 0, stream>>>(
        x, Wv, Wo, x_bf, Wv_bf, Wo_bf);

    // 2. v = x @ Wv^T (bf16 out) + fused per-chunk rotor sums
    gemm1_fused<<<(BT_ / 128) * (D_ / 128), 256, 0, stream>>>(
        (const short*)x_bf, (const short*)Wv_bf, v_bf, freqs, csum);

    // 3. prefix + replay + unbind
    dim3 p3grid(NCHUNK_, D_ / 512, B_);
    scan_pass3<<<p3grid, 256, 0, stream>>>(v_bf, freqs, csum, ret);

    // 4. out = retrieved @ Wo^T (fp32 out)
    gemm2_plain<<<(BT_ / 128) * (D_ / 128), 256, 0, stream>>>(
        (const short*)ret, (const short*)Wo_bf, out);
}